// Round 1
// 83.497 us; speedup vs baseline: 1.0010x; 1.0010x over previous
//
#include <hip/hip_runtime.h>
#include <hip/hip_bf16.h>
#include <math.h>

// Problem constants (from reference)
#define INPUT_DIM 30000
#define UNITS     2048
#define NNZ       500000
#define BATCH     32

// ---------------------------------------------------------------------------
// Kernel 1: transpose x [32][30000] -> xt [30000][32] (LDS-tiled, coalesced
// both sides) + zero the ws2/spill accumulator arrays (131072 floats).
// ---------------------------------------------------------------------------
__global__ __launch_bounds__(256) void transpose_k(const float* __restrict__ x,
                                                   float* __restrict__ xt,
                                                   float4* __restrict__ zero4) {
    // zero ws2 + spill: 32768 float4
    {
        int g = blockIdx.x * 256 + threadIdx.x;
        if (g < 32768) zero4[g] = make_float4(0.f, 0.f, 0.f, 0.f);
    }
    __shared__ float tile[32][65];                // +1 pad: conflict-free
    const int i0 = blockIdx.x * 64;
    const int t  = threadIdx.x;
    const int w  = t >> 6;                        // wave 0..3
    const int l  = t & 63;                        // lane
    const bool iok = (i0 + l) < INPUT_DIM;
    #pragma unroll
    for (int bb = 0; bb < 8; ++bb) {              // 8 batch rows per wave
        int b = w * 8 + bb;
        tile[b][l] = iok ? x[b * INPUT_DIM + i0 + l] : 0.f;
    }
    __syncthreads();
    float4* __restrict__ xt4 = (float4*)xt;
    #pragma unroll
    for (int rep = 0; rep < 2; ++rep) {
        int f  = t + rep * 256;                   // 0..511 float4 slots
        int il = f >> 3;                          // local i 0..63
        int b4 = f & 7;                           // batch quad 0..7
        if (i0 + il < INPUT_DIM)
            xt4[(size_t)(i0 + il) * 8 + b4] =
                make_float4(tile[b4 * 4 + 0][il], tile[b4 * 4 + 1][il],
                            tile[b4 * 4 + 2][il], tile[b4 * 4 + 3][il]);
    }
}

// ---------------------------------------------------------------------------
// Kernel 2: residue-sliced scatter with REGISTER accumulation.
// R5 restructure: every iteration runs COLD (the harness's 256 MiB poison
// fill exactly flushes the LLC), so the ~1M random 64B xt-row segments are
// ~900-cy HBM misses and the kernel is bound by outstanding-miss concurrency,
// not bandwidth. The old 2-round K-loop serialized 4 dependent HBM round
// trips (idx -> gather, twice). New schedule: straight-line — issue ALL 8
// idx int4 + 8 kv loads up front, then ALL 16 float4 gathers back-to-back
// (sched_barrier pins them above the FMAs), then accumulate. One idx-wait +
// one gather-wait on the critical path, 16 gathers in flight per wave.
// col0 correctness fallback (global-atomic spill) unchanged.
// Grid: 512 WGs x 512 thr; thread = (rl 0..3, bg 0..3, es 0..31).
// ---------------------------------------------------------------------------
__global__ __launch_bounds__(512) void scatter_k(const int* __restrict__ idx,
                                                 const float* __restrict__ kv,
                                                 const float* __restrict__ xt,
                                                 float* __restrict__ ws2,
                                                 float* __restrict__ spill) {
    __shared__ float part[32 * 128];              // [es][b 0..31][rl 0..3]
    __shared__ int   colA[4];

    const int t    = threadIdx.x;
    const int rl   = t & 3;
    const int bg   = (t >> 2) & 3;
    const int es   = t >> 4;                      // 0..31
    const int r    = blockIdx.x * 4 + rl;         // residue 0..2047
    const int boff = bg * 8;

    // int64 vs int32 index detection (uniform): int64 LE -> high words zero.
    const bool is64 = ((idx[3] | idx[5] | idx[7]) == 0);
    const int  col0 = is64 ? idx[4 * r + 2] : idx[2 * r + 1];

    // ---- phase A: all 8 idx/kv loads issued together (independent) ----
    const int base = r + UNITS * es;              // 0..65535
    int   rows[8], cols[8];
    float vals[8];
    if (is64) {
        const int4* __restrict__ p = (const int4*)idx;
        #pragma unroll
        for (int j = 0; j < 8; ++j) {
            int  e  = base + j * 65536;           // entry stripe, step 2048*32
            bool ok = e < NNZ;
            int4 q  = ok ? p[e] : make_int4(0, 0, col0, 0);
            rows[j] = q.x; cols[j] = q.z;
            vals[j] = ok ? kv[e] : 0.f;
        }
    } else {
        const int2* __restrict__ p = (const int2*)idx;
        #pragma unroll
        for (int j = 0; j < 8; ++j) {
            int  e  = base + j * 65536;
            bool ok = e < NNZ;
            int2 q  = ok ? p[e] : make_int2(0, col0);
            rows[j] = q.x; cols[j] = q.y;
            vals[j] = ok ? kv[e] : 0.f;
        }
    }

    // ---- phase B: all 16 gathers in flight (32B/lane; 4 bg threads jointly
    // cover each entry's full 128B xt row) ----
    float4 g0[8], g1[8];
    #pragma unroll
    for (int j = 0; j < 8; ++j) {
        const float4* __restrict__ xr = (const float4*)(xt + rows[j] * 32 + boff);
        g0[j] = xr[0];
        g1[j] = xr[1];
    }
    // keep every gather issued before the first FMA consumes one
    __builtin_amdgcn_sched_barrier(0);

    // ---- phase C: accumulate ----
    float acc[8];
    #pragma unroll
    for (int k = 0; k < 8; ++k) acc[k] = 0.f;

    #pragma unroll
    for (int j = 0; j < 8; ++j) {
        float v = vals[j];
        if (cols[j] == col0) {                    // uniformly true for this data
            acc[0] += v * g0[j].x; acc[1] += v * g0[j].y;
            acc[2] += v * g0[j].z; acc[3] += v * g0[j].w;
            acc[4] += v * g1[j].x; acc[5] += v * g1[j].y;
            acc[6] += v * g1[j].z; acc[7] += v * g1[j].w;
        } else {                                  // correctness fallback
            float* __restrict__ sp = spill + cols[j];
            atomicAdd(sp + (boff + 0) * UNITS, v * g0[j].x);
            atomicAdd(sp + (boff + 1) * UNITS, v * g0[j].y);
            atomicAdd(sp + (boff + 2) * UNITS, v * g0[j].z);
            atomicAdd(sp + (boff + 3) * UNITS, v * g0[j].w);
            atomicAdd(sp + (boff + 4) * UNITS, v * g1[j].x);
            atomicAdd(sp + (boff + 5) * UNITS, v * g1[j].y);
            atomicAdd(sp + (boff + 6) * UNITS, v * g1[j].z);
            atomicAdd(sp + (boff + 7) * UNITS, v * g1[j].w);
        }
    }

    // combine 32 es-stripes via plain LDS writes (one-time; conflicts cheap)
    #pragma unroll
    for (int bb = 0; bb < 8; ++bb)
        part[es * 128 + (boff + bb) * 4 + rl] = acc[bb];
    if (t < 4) colA[t] = col0;
    __syncthreads();

    if (t < 128) {
        const int rr = t & 3;
        const int b  = t >> 2;                    // 0..31
        float s = 0.f;
        #pragma unroll
        for (int e = 0; e < 32; ++e) s += part[e * 128 + b * 4 + rr];
        // one atomic per (b, col); distinct addrs when cols are bijective
        atomicAdd(&ws2[b * UNITS + colA[rr]], s);
    }
}

// ---------------------------------------------------------------------------
// Kernel 3: out = tanh(ws2 + spill + bias), fully coalesced. 65536 elements.
// ---------------------------------------------------------------------------
__global__ __launch_bounds__(256) void final_k(const float* __restrict__ ws2,
                                               const float* __restrict__ spill,
                                               const float* __restrict__ bias,
                                               float* __restrict__ out) {
    int tid = blockIdx.x * 256 + threadIdx.x;     // 0..65535
    int c   = tid & (UNITS - 1);
    out[tid] = tanhf(ws2[tid] + spill[tid] + bias[c]);
}

// ---------------------------------------------------------------------------
extern "C" void kernel_launch(void* const* d_in, const int* in_sizes, int n_in,
                              void* d_out, int out_size, void* d_ws, size_t ws_size,
                              hipStream_t stream) {
    const float* x    = (const float*)d_in[0];
    const float* kv   = (const float*)d_in[1];
    const float* bias = (const float*)d_in[2];
    const int*   idx  = (const int*)d_in[3];
    float*       out  = (float*)d_out;

    // workspace layout: xt [960000 f] | ws2 [65536 f] | spill [65536 f]
    float* xt    = (float*)d_ws;
    float* ws2   = xt + (size_t)INPUT_DIM * BATCH;
    float* spill = ws2 + BATCH * UNITS;

    transpose_k<<<(INPUT_DIM + 63) / 64, 256, 0, stream>>>(x, xt, (float4*)ws2);
    scatter_k<<<UNITS / 4, 512, 0, stream>>>(idx, kv, xt, ws2, spill);
    final_k<<<(BATCH * UNITS) / 256, 256, 0, stream>>>(ws2, spill, bias, out);
}